// Round 1
// baseline (9657.675 us; speedup 1.0000x reference)
//
#include <hip/hip_runtime.h>

typedef __attribute__((ext_vector_type(4))) float f32x4;
typedef __attribute__((ext_vector_type(8))) short s16x8;

__device__ __forceinline__ unsigned short f2bf(float f) {
  union { float f; unsigned u; } v; v.f = f;
  unsigned r = v.u + 0x7fffu + ((v.u >> 16) & 1u);
  return (unsigned short)(r >> 16);
}

// ---------------- prep kernels ----------------

// Wbig[c] (1024x512) = [hcomb_W[c]; W_hh[c] @ hcomb_W[c]] as bf16
// bbig[c] (1024)     = [hcomb_b[c]; W_hh[c] @ hcomb_b[c] + b_hh[c]]
__global__ void prep_wbig(const float* __restrict__ hcomb_W, const float* __restrict__ hcomb_b,
                          const float* __restrict__ W_hh, const float* __restrict__ b_hh,
                          unsigned short* __restrict__ Wbig, float* __restrict__ bbig) {
  __shared__ float red[256];
  const int c = blockIdx.x, g = blockIdx.y, t = threadIdx.x;
  const float* hW = hcomb_W + (size_t)c * 256 * 512;
  unsigned short* orow = Wbig + ((size_t)c * 1024 + g) * 512;
  if (g < 256) {
    orow[t]       = f2bf(hW[(size_t)g * 512 + t]);
    orow[t + 256] = f2bf(hW[(size_t)g * 512 + t + 256]);
    if (t == 0) bbig[c * 1024 + g] = hcomb_b[c * 256 + g];
    return;
  }
  const int gp = g - 256;
  const float* wrow = W_hh + ((size_t)c * 768 + gp) * 256;
  float a0 = 0.f, a1 = 0.f;
  for (int h = 0; h < 256; h++) {
    float w = wrow[h];
    a0 += w * hW[(size_t)h * 512 + t];
    a1 += w * hW[(size_t)h * 512 + t + 256];
  }
  orow[t] = f2bf(a0); orow[t + 256] = f2bf(a1);
  red[t] = wrow[t] * hcomb_b[c * 256 + t];
  __syncthreads();
  for (int s = 128; s > 0; s >>= 1) { if (t < s) red[t] += red[t + s]; __syncthreads(); }
  if (t == 0) bbig[c * 1024 + g] = red[0] + b_hh[c * 768 + gp];
}

// U_{l,a}[c][v][f] = sum_e emb[c][v][e] * xcomb_W[c][f][side*256 + e]
__global__ void prep_u(const float* __restrict__ emb, const float* __restrict__ xcomb_W,
                       float* __restrict__ Ul, float* __restrict__ Ua) {
  __shared__ float er[256];
  const int c = blockIdx.x, v = blockIdx.y, side = blockIdx.z, f = threadIdx.x;
  er[f] = emb[((size_t)c * 257 + v) * 256 + f];
  __syncthreads();
  const float* wrow = xcomb_W + ((size_t)c * 256 + f) * 512 + side * 256;
  float a = 0.f;
  for (int e = 0; e < 256; e++) a += er[e] * wrow[e];
  (side ? Ua : Ul)[((size_t)c * 257 + v) * 256 + f] = a;
}

// T_{l,a}[c][v][g] = sum_f W_ih[c][g][f] * U[c][v][f]
__global__ void prep_t(const float* __restrict__ W_ih, const float* __restrict__ Ul,
                       const float* __restrict__ Ua, float* __restrict__ Tl, float* __restrict__ Ta) {
  __shared__ float ur[256];
  const int c = blockIdx.x, v = blockIdx.y, side = blockIdx.z, g = threadIdx.x; // block 768
  if (g < 256) ur[g] = (side ? Ua : Ul)[((size_t)c * 257 + v) * 256 + g];
  __syncthreads();
  const float* wrow = W_ih + ((size_t)c * 768 + g) * 258;
  float a = 0.f;
  for (int f = 0; f < 256; f++) a += ur[f] * wrow[f];
  (side ? Ta : Tl)[((size_t)c * 257 + v) * 768 + g] = a;
}

// bgx[c][g] = b_ih[c][g] + sum_f W_ih[c][g][f] * xcomb_b[c][f]
__global__ void prep_bgx(const float* __restrict__ W_ih, const float* __restrict__ xcomb_b,
                         const float* __restrict__ b_ih, float* __restrict__ bgx) {
  __shared__ float xb[256];
  const int c = blockIdx.x, g = threadIdx.x; // block 768
  if (g < 256) xb[g] = xcomb_b[c * 256 + g];
  __syncthreads();
  const float* wrow = W_ih + ((size_t)c * 768 + g) * 258;
  float a = b_ih[c * 768 + g];
  for (int f = 0; f < 256; f++) a += xb[f] * wrow[f];
  bgx[c * 768 + g] = a;
}

// TG[v][u]  = emb[0][v] . green_W[u][256:512]
// TB0[v][u] = emb[0][v] . blue_W[u][256:512]
// TB1[v][u] = emb[1][v] . blue_W[u][512:768]
__global__ void prep_tgb(const float* __restrict__ emb, const float* __restrict__ green_W,
                         const float* __restrict__ blue_W,
                         float* __restrict__ TG, float* __restrict__ TB0, float* __restrict__ TB1) {
  __shared__ float er[256];
  const int v = blockIdx.x, which = blockIdx.y, u = threadIdx.x; // block 320
  const int ch = (which == 2) ? 1 : 0;
  if (u < 256) er[u] = emb[((size_t)ch * 257 + v) * 256 + u];
  __syncthreads();
  if (u >= 257) return;
  const float* W; int pitch, off; float* T;
  if (which == 0)      { W = green_W; pitch = 512; off = 256; T = TG;  }
  else if (which == 1) { W = blue_W;  pitch = 768; off = 256; T = TB0; }
  else                 { W = blue_W;  pitch = 768; off = 512; T = TB1; }
  const float* wrow = W + (size_t)u * pitch + off;
  float a = 0.f;
  for (int e = 0; e < 256; e++) a += er[e] * wrow[e];
  T[(size_t)v * 257 + u] = a;
}

// W3[c] (272x256) bf16 = h-part of {red_W, green_W, blue_W}; rows >=257 zero
__global__ void prep_w3(const float* __restrict__ red_W, const float* __restrict__ green_W,
                        const float* __restrict__ blue_W, unsigned short* __restrict__ W3) {
  const int c = blockIdx.x, v = blockIdx.y, t = threadIdx.x; // block 256
  float val = 0.f;
  if (v < 257) {
    if (c == 0)      val = red_W[(size_t)v * 256 + t];
    else if (c == 1) val = green_W[(size_t)v * 512 + t];
    else             val = blue_W[(size_t)v * 768 + t];
  }
  W3[((size_t)c * 272 + v) * 256 + t] = f2bf(val);
}

// ---------------- main level kernel ----------------
// level L: step WGs (role 0..3) process cells (r,k,c) with r+3k+c==L
//          epi  WG  (role 4)    writes logits for cells with r+3k+c==L-1
__global__ __launch_bounds__(256, 2)
void level_kernel(int L, const int* __restrict__ x,
                  float* __restrict__ hbuf,
                  const unsigned short* __restrict__ Wbig,
                  const float* __restrict__ bbig,
                  const float* __restrict__ Tl, const float* __restrict__ Ta,
                  const float* __restrict__ bgx,
                  const float* __restrict__ W_ih,
                  const unsigned short* __restrict__ W3,
                  const float* __restrict__ TG, const float* __restrict__ TB0,
                  const float* __restrict__ TB1,
                  const float* __restrict__ red_b, const float* __restrict__ green_b,
                  const float* __restrict__ blue_b,
                  float* __restrict__ out)
{
  __shared__ unsigned short Abuf[128 * 136];
  __shared__ int idx0[128], idx1[128];

  const int r = blockIdx.x;
  const int role = blockIdx.y;
  const int tid = threadIdx.x;
  const int lane = tid & 63, wv = tid >> 6;
  const int quad = lane >> 4, l16 = lane & 15;

  if (role < 4) {
    // ---------------- recurrent step ----------------
    const int t = L - r;
    if (t < 0 || t > 92) return;
    const int k = t / 3, c = t - 3 * k;

    if (tid < 128) {
      const int b = tid;
      idx0[b] = x[((b * 3 + c) * 32 + (r + 1)) * 32 + k];       // left index
      idx1[b] = x[((b * 3 + c) * 32 + r) * 32 + (k + 1)];       // above index
    }

    const int jcol = role * 64 + wv * 16;    // wave's 16-col slice within H
    const bool pl_zero = (k == 0 && c == 0);
    const bool a_zero  = (r == 0);
    const float* plp = hbuf + ((size_t)(r * 3 + (c == 0 ? 2 : c - 1)) * 128) * 256;
    const float* ap  = (r > 0) ? hbuf + ((size_t)((r - 1) * 3 + c) * 128) * 256 : hbuf;

    f32x4 acc[8][4];
    #pragma unroll
    for (int mt = 0; mt < 8; mt++)
      #pragma unroll
      for (int g = 0; g < 4; g++)
        #pragma unroll
        for (int e = 0; e < 4; e++) acc[mt][g][e] = 0.f;

    const unsigned short* Wb = Wbig + (size_t)c * 1024 * 512;

    for (int kc = 0; kc < 4; kc++) {
      const bool from_pl = (kc < 2);
      const float* src = from_pl ? plp : ap;
      const bool zero = from_pl ? pl_zero : a_zero;
      const int colbase = from_pl ? kc * 128 : (kc - 2) * 128;
      __syncthreads();
      #pragma unroll 4
      for (int it = 0; it < 16; it++) {
        const int li = it * 256 + tid;
        const int row = li >> 5;
        const int col = (li & 31) * 4;
        unsigned short o0 = 0, o1 = 0, o2 = 0, o3 = 0;
        if (!zero) {
          const float4 v = *(const float4*)(src + (size_t)row * 256 + colbase + col);
          o0 = f2bf(v.x); o1 = f2bf(v.y); o2 = f2bf(v.z); o3 = f2bf(v.w);
        }
        unsigned short* d = &Abuf[row * 136 + col];
        d[0] = o0; d[1] = o1; d[2] = o2; d[3] = o3;
      }
      __syncthreads();
      #pragma unroll
      for (int ks = 0; ks < 4; ks++) {
        const int kofs = ks * 32 + quad * 8;
        s16x8 bf[4];
        #pragma unroll
        for (int g = 0; g < 4; g++)
          bf[g] = *(const s16x8*)(Wb + (size_t)(g * 256 + jcol + l16) * 512 + kc * 128 + kofs);
        #pragma unroll
        for (int mt = 0; mt < 8; mt++) {
          const s16x8 af = *(const s16x8*)&Abuf[(mt * 16 + l16) * 136 + kofs];
          #pragma unroll
          for (int g = 0; g < 4; g++)
            acc[mt][g] = __builtin_amdgcn_mfma_f32_16x16x32_bf16(af, bf[g], acc[mt][g], 0, 0, 0);
        }
      }
    }

    // GRU epilogue (per-lane column j fixed)
    const int j = jcol + l16;
    const float bh = bbig[c * 1024 + j];
    const float br = bbig[c * 1024 + 256 + j];
    const float bz = bbig[c * 1024 + 512 + j];
    const float bn = bbig[c * 1024 + 768 + j];
    const float fr = (float)r, fk = (float)k;
    const float gxr0 = bgx[c * 768 + j] +
        fr * W_ih[((size_t)c * 768 + j) * 258 + 256] + fk * W_ih[((size_t)c * 768 + j) * 258 + 257];
    const float gxz0 = bgx[c * 768 + 256 + j] +
        fr * W_ih[((size_t)c * 768 + 256 + j) * 258 + 256] + fk * W_ih[((size_t)c * 768 + 256 + j) * 258 + 257];
    const float gxn0 = bgx[c * 768 + 512 + j] +
        fr * W_ih[((size_t)c * 768 + 512 + j) * 258 + 256] + fk * W_ih[((size_t)c * 768 + 512 + j) * 258 + 257];
    const float* Tlc = Tl + (size_t)c * 257 * 768;
    const float* Tac = Ta + (size_t)c * 257 * 768;
    float* hout = hbuf + ((size_t)(r * 3 + c) * 128) * 256;

    #pragma unroll
    for (int mt = 0; mt < 8; mt++) {
      #pragma unroll
      for (int i = 0; i < 4; i++) {
        const int b = mt * 16 + quad * 4 + i;
        const int xl = idx0[b], xa = idx1[b];
        const float gxr = gxr0 + Tlc[(size_t)xl * 768 + j] + Tac[(size_t)xa * 768 + j];
        const float gxz = gxz0 + Tlc[(size_t)xl * 768 + 256 + j] + Tac[(size_t)xa * 768 + 256 + j];
        const float gxn = gxn0 + Tlc[(size_t)xl * 768 + 512 + j] + Tac[(size_t)xa * 768 + 512 + j];
        const float h   = acc[mt][0][i] + bh;
        const float ghr = acc[mt][1][i] + br;
        const float ghz = acc[mt][2][i] + bz;
        const float ghn = acc[mt][3][i] + bn;
        const float rg = __fdividef(1.f, 1.f + __expf(-(gxr + ghr)));
        const float zg = __fdividef(1.f, 1.f + __expf(-(gxz + ghz)));
        const float ng = 1.f - __fdividef(2.f, __expf(2.f * (gxn + rg * ghn)) + 1.f);
        hout[(size_t)b * 256 + j] = (1.f - zg) * ng + zg * h;
      }
    }
  } else {
    // ---------------- logits epilogue for level L-1 cells ----------------
    const int t = (L - 1) - r;
    if (L < 1 || t < 0 || t > 92) return;
    const int k = t / 3, c = t - 3 * k;

    if (tid < 128) {
      const int b = tid;
      idx0[b] = x[((b * 3 + 0) * 32 + (r + 1)) * 32 + (k + 1)];  // target ch0
      idx1[b] = x[((b * 3 + 1) * 32 + (r + 1)) * 32 + (k + 1)];  // target ch1
    }

    const float* hsrc = hbuf + ((size_t)(r * 3 + c) * 128) * 256;
    const unsigned short* W3c = W3 + (size_t)c * 272 * 256;

    f32x4 acc[2][17];
    #pragma unroll
    for (int m2 = 0; m2 < 2; m2++)
      #pragma unroll
      for (int nt = 0; nt < 17; nt++)
        #pragma unroll
        for (int e = 0; e < 4; e++) acc[m2][nt][e] = 0.f;

    for (int kc = 0; kc < 2; kc++) {
      __syncthreads();
      #pragma unroll 4
      for (int it = 0; it < 16; it++) {
        const int li = it * 256 + tid;
        const int row = li >> 5;
        const int col = (li & 31) * 4;
        const float4 v = *(const float4*)(hsrc + (size_t)row * 256 + kc * 128 + col);
        unsigned short* d = &Abuf[row * 136 + col];
        d[0] = f2bf(v.x); d[1] = f2bf(v.y); d[2] = f2bf(v.z); d[3] = f2bf(v.w);
      }
      __syncthreads();
      #pragma unroll
      for (int ks = 0; ks < 4; ks++) {
        const int kofs = ks * 32 + quad * 8;
        s16x8 af[2];
        #pragma unroll
        for (int m2 = 0; m2 < 2; m2++)
          af[m2] = *(const s16x8*)&Abuf[((wv * 2 + m2) * 16 + l16) * 136 + kofs];
        #pragma unroll
        for (int nt = 0; nt < 17; nt++) {
          const s16x8 bf = *(const s16x8*)(W3c + (size_t)(nt * 16 + l16) * 256 + kc * 128 + kofs);
          #pragma unroll
          for (int m2 = 0; m2 < 2; m2++)
            acc[m2][nt] = __builtin_amdgcn_mfma_f32_16x16x32_bf16(af[m2], bf, acc[m2][nt], 0, 0, 0);
        }
      }
    }

    const float* bias = (c == 0) ? red_b : (c == 1) ? green_b : blue_b;
    #pragma unroll
    for (int m2 = 0; m2 < 2; m2++) {
      #pragma unroll
      for (int i = 0; i < 4; i++) {
        const int b = (wv * 2 + m2) * 16 + quad * 4 + i;
        const int t0 = idx0[b], t1 = idx1[b];
        float* orow = out + ((size_t)((b * 3 + c) * 31 + r) * 31 + k) * 257;
        #pragma unroll
        for (int nt = 0; nt < 17; nt++) {
          const int v = nt * 16 + l16;
          if (v < 257) {
            float val = acc[m2][nt][i] + bias[v];
            if (c == 1)      val += TG[(size_t)t0 * 257 + v];
            else if (c == 2) val += TB0[(size_t)t0 * 257 + v] + TB1[(size_t)t1 * 257 + v];
            orow[v] = val;
          }
        }
      }
    }
  }
}

// ---------------- host launch ----------------

extern "C" void kernel_launch(void* const* d_in, const int* in_sizes, int n_in,
                              void* d_out, int out_size, void* d_ws, size_t ws_size,
                              hipStream_t stream) {
  const int*   x       = (const int*)  d_in[0];
  const float* emb     = (const float*)d_in[1];
  const float* xcomb_W = (const float*)d_in[2];
  const float* xcomb_b = (const float*)d_in[3];
  const float* hcomb_W = (const float*)d_in[4];
  const float* hcomb_b = (const float*)d_in[5];
  const float* W_ih    = (const float*)d_in[6];
  const float* W_hh    = (const float*)d_in[7];
  const float* b_ih    = (const float*)d_in[8];
  const float* b_hh    = (const float*)d_in[9];
  const float* red_W   = (const float*)d_in[10];
  const float* red_b   = (const float*)d_in[11];
  const float* green_W = (const float*)d_in[12];
  const float* green_b = (const float*)d_in[13];
  const float* blue_W  = (const float*)d_in[14];
  const float* blue_b  = (const float*)d_in[15];
  float* out = (float*)d_out;

  char* p = (char*)d_ws;
  auto alloc = [&](size_t bytes) -> char* {
    char* r = p; p += (bytes + 255) & ~(size_t)255; return r;
  };
  float* hbuf          = (float*)alloc((size_t)31 * 3 * 128 * 256 * 4);
  unsigned short* Wbig = (unsigned short*)alloc((size_t)3 * 1024 * 512 * 2);
  float* bbig          = (float*)alloc((size_t)3 * 1024 * 4);
  float* Tl            = (float*)alloc((size_t)3 * 257 * 768 * 4);
  float* Ta            = (float*)alloc((size_t)3 * 257 * 768 * 4);
  float* Ul            = (float*)alloc((size_t)3 * 257 * 256 * 4);
  float* Ua            = (float*)alloc((size_t)3 * 257 * 256 * 4);
  float* bgx           = (float*)alloc((size_t)3 * 768 * 4);
  unsigned short* W3   = (unsigned short*)alloc((size_t)3 * 272 * 256 * 2);
  float* TG            = (float*)alloc((size_t)257 * 257 * 4);
  float* TB0           = (float*)alloc((size_t)257 * 257 * 4);
  float* TB1           = (float*)alloc((size_t)257 * 257 * 4);

  prep_wbig<<<dim3(3, 1024), dim3(256), 0, stream>>>(hcomb_W, hcomb_b, W_hh, b_hh, Wbig, bbig);
  prep_u<<<dim3(3, 257, 2), dim3(256), 0, stream>>>(emb, xcomb_W, Ul, Ua);
  prep_t<<<dim3(3, 257, 2), dim3(768), 0, stream>>>(W_ih, Ul, Ua, Tl, Ta);
  prep_bgx<<<dim3(3), dim3(768), 0, stream>>>(W_ih, xcomb_b, b_ih, bgx);
  prep_tgb<<<dim3(257, 3), dim3(320), 0, stream>>>(emb, green_W, blue_W, TG, TB0, TB1);
  prep_w3<<<dim3(3, 272), dim3(256), 0, stream>>>(red_W, green_W, blue_W, W3);

  for (int L = 0; L < 124; L++) {
    level_kernel<<<dim3(31, 5), dim3(256), 0, stream>>>(
        L, x, hbuf, Wbig, bbig, Tl, Ta, bgx, W_ih, W3, TG, TB0, TB1,
        red_b, green_b, blue_b, out);
  }
}